// Round 10
// baseline (78222.742 us; speedup 1.0000x reference)
//
#include <hip/hip_runtime.h>
#include <cstdint>
#include <cstddef>

namespace {
constexpr int Dh = 512;   // hidden / emb dim
constexpr int G3 = 1536;  // 3*Dh
constexpr int NB = 256;   // batch
constexpr int SL = 256;   // src len
constexpr int TL = 256;   // trg len
constexpr int NV = 512;   // vocab
}

typedef __attribute__((ext_vector_type(8))) short bf16x8;
typedef __attribute__((ext_vector_type(4))) float f32x4;
typedef unsigned long long u64t;

__device__ __forceinline__ unsigned short f2bf(float f) {
  unsigned int u = __float_as_uint(f);
  u = (u + 0x7FFFu + ((u >> 16) & 1u)) >> 16;  // RNE (finite, small values)
  return (unsigned short)u;
}
__device__ __forceinline__ float bf2f(unsigned short s) {
  return __uint_as_float(((unsigned int)s) << 16);
}

// sc0-only store: bypass L1, write XCD-shared L2 (write-back, no sc1 drain).
__device__ __forceinline__ void store_u32_sc0(unsigned int* p, unsigned v) {
  asm volatile("global_store_dword %0, %1, off sc0" :: "v"(p), "v"(v) : "memory");
}

// gi packed layout (consumer-native): [s][b][dt32(16)][l15(16)][8]
// slot n*3+g (n = d16-half within 32-d tile, g = gate), slots 6,7 padding.

// f32 -> bf16 elementwise (optional relu), 4 elems/thread
__global__ __launch_bounds__(256) void cvt_bf16(const float* __restrict__ in,
                                                unsigned short* __restrict__ out,
                                                int n4, int relu) {
  int i = blockIdx.x * 256 + threadIdx.x;
  if (i >= n4) return;
  float4 v = ((const float4*)in)[i];
  if (relu) {
    v.x = fmaxf(v.x, 0.f); v.y = fmaxf(v.y, 0.f);
    v.z = fmaxf(v.z, 0.f); v.w = fmaxf(v.w, 0.f);
  }
  ushort4 o;
  o.x = f2bf(v.x); o.y = f2bf(v.y); o.z = f2bf(v.z); o.w = f2bf(v.w);
  ((ushort4*)out)[i] = o;
}

// Pack Whh (bf16 [1536][512] native) into lane-major fragment order:
// Wpk[dt(16)][slot(6)][kk(16)][lane(64)][8], slot = n*3+g.
__global__ __launch_bounds__(256) void pack_whh(const unsigned short* __restrict__ Wb,
                                                unsigned short* __restrict__ Wpk) {
  const int idx = blockIdx.x * 256 + threadIdx.x;  // 16*6*16*64 = 98304 fragments
  if (idx >= 16 * 6 * 16 * 64) return;
  const int dt = idx / 6144;
  const int rem = idx - dt * 6144;
  const int slot = rem >> 10;
  const int kk = (rem >> 6) & 15;
  const int l = rem & 63;
  const int n = slot / 3, g = slot - n * 3;
  const int row = g * 512 + dt * 32 + n * 16 + (l & 15);
  const int k = kk * 32 + (l >> 4) * 8;
  *(uint4*)(Wpk + (size_t)idx * 8) = *(const uint4*)(Wb + (size_t)row * Dh + k);
}

// C[M,N] = A(bf16) @ W(bf16 [N][K] native rows)^T-as-B + bias, K = 512.
// MFMA 16x16x32. 128x128 tile, BK=64, 4 waves (2x2 x 64x64 quadrants).
// AMODE 0: A row = Abase + idx[row]*K (embedding gather), row m = b*256 + s
// AMODE 1: A row = Abase + ((row&255)*NB + (row>>8))*K (hb_all[t][b], row=b*TL+t)
// OMODE 0: fp32 at row*N+col   OMODE 2: bf16 scattered to packed gi layout
template <int AMODE, int OMODE>
__global__ __launch_bounds__(256) void gemm_bf16(
    const unsigned short* __restrict__ Abase, const int* __restrict__ idx,
    const unsigned short* __restrict__ W, const float* __restrict__ bias,
    void* __restrict__ Cout, int N) {
  __shared__ unsigned short lds_a[8 * 128 * 8];  // 16 KB
  __shared__ unsigned short lds_b[8 * 128 * 8];  // 16 KB
  const int t = threadIdx.x;
  const int n0 = blockIdx.x * 128;
  const int m0 = blockIdx.y * 128;
  const int w = t >> 6, l = t & 63;
  const int mq = (w & 1) * 64, nq = (w >> 1) * 64;
  const int l15 = l & 15, lh = l >> 4;

  const int sm = t & 127;
  const int sk = (t >> 7) * 4;
  const unsigned short* arow;
  if (AMODE == 0) {
    arow = Abase + (size_t)idx[m0 + sm] * Dh;
  } else {
    int row = m0 + sm;
    arow = Abase + ((size_t)(row & 255) * NB + (row >> 8)) * Dh;
  }
  const unsigned short* brow = W + (size_t)(n0 + sm) * Dh;

  f32x4 acc[4][4];
#pragma unroll
  for (int i = 0; i < 4; ++i)
#pragma unroll
    for (int j = 0; j < 4; ++j) acc[i][j] = (f32x4)0.f;

  for (int k0 = 0; k0 < Dh; k0 += 64) {
    __syncthreads();
#pragma unroll
    for (int i = 0; i < 4; ++i) {
      int kc = sk + i;
      *(uint4*)&lds_a[(kc * 128 + sm) * 8] = *(const uint4*)(arow + k0 + kc * 8);
      *(uint4*)&lds_b[(kc * 128 + sm) * 8] = *(const uint4*)(brow + k0 + kc * 8);
    }
    __syncthreads();
#pragma unroll
    for (int q = 0; q < 2; ++q) {
      bf16x8 af[4], bfr[4];
#pragma unroll
      for (int i = 0; i < 4; ++i)
        af[i] = *(const bf16x8*)&lds_a[((q * 4 + lh) * 128 + mq + i * 16 + l15) * 8];
#pragma unroll
      for (int j = 0; j < 4; ++j)
        bfr[j] = *(const bf16x8*)&lds_b[((q * 4 + lh) * 128 + nq + j * 16 + l15) * 8];
#pragma unroll
      for (int i = 0; i < 4; ++i)
#pragma unroll
        for (int j = 0; j < 4; ++j)
          acc[i][j] = __builtin_amdgcn_mfma_f32_16x16x32_bf16(af[i], bfr[j], acc[i][j], 0, 0, 0);
    }
  }

#pragma unroll
  for (int j = 0; j < 4; ++j) {
    const int col = n0 + nq + j * 16 + l15;
    const float bv = bias[col];
#pragma unroll
    for (int i = 0; i < 4; ++i) {
#pragma unroll
      for (int r = 0; r < 4; ++r) {
        const int row = m0 + mq + i * 16 + lh * 4 + r;
        const float v = acc[i][j][r] + bv;
        if (OMODE == 0) {
          ((float*)Cout)[(size_t)row * N + col] = v;
        } else {
          const int b = row >> 8, s = row & 255;      // row = b*256 + s
          const int g = col >> 9, d = col & 511;
          const int dt = d >> 5, nn_ = (d >> 4) & 1, cl = d & 15;
          ((unsigned short*)Cout)[((((size_t)s * NB + b) * 16 + dt) * 16 + cl) * 8 + nn_ * 3 + g] = f2bf(v);
        }
      }
    }
  }
}

// ---- Persistent GRU phase v5: rotation + sc0 (XCD-L2) exchange. ----
// 256 WGs x 64 thr, 96KB LDS => 1 WG/CU. Group = bid&15 (16 batches);
// member dt = bid>>4. Publish via explicit sc0 stores (bypass L1, dirty in
// shared XCD L2, no L3 drain); poll via sc0 loads; data loads plain (L1-cold
// by rotation). Fast path gated by XCC_ID discovery; else SYSTEM path (R7).
// Fast polls bounded: on watchdog trip -> sticky broken, finish fast (fails
// validation visibly instead of hanging).
__global__ __launch_bounds__(64, 1) void gru_persist5(
    const unsigned short* __restrict__ Wpk,   // [16][6][16][64][8] packed
    const unsigned short* __restrict__ gi,    // packed [s][b][dt][l15][8] (incl. bih)
    const float* __restrict__ bhh,
    const float* __restrict__ h32_init,       // fp32 init (null -> zeros)
    float* __restrict__ h32_final,            // fp32 out (or null)
    const unsigned short* __restrict__ rd0,   // step-0 h source (zeros or enc final)
    unsigned short* __restrict__ roll,        // [256][NB][Dh] rotation (+archive)
    unsigned int* __restrict__ flags,         // [256][16][16] pre-zeroed
    unsigned int* __restrict__ xcdbuf,        // [16][16] pre-zeroed
    unsigned int* __restrict__ dflags,        // [16][16] pre-zeroed (discovery)
    int nsteps) {
  __shared__ unsigned short wl[6 * 16 * 64 * 8];  // 96 KB
  const int wt = blockIdx.x;                // 0..255
  const int grp = wt & 15;                  // batch group (shares bid%8 -> XCD)
  const int dt = wt >> 4;                   // d-slice
  const int b0 = grp * 16;
  const int d0 = dt * 32;
  const int l = threadIdx.x;                // 0..63
  const int l15 = l & 15, lh = l >> 4;

  // ---- stage W slice to LDS once ----
  {
    const uint4* wsrc = (const uint4*)(Wpk + (size_t)dt * 49152);
    uint4* wdst = (uint4*)wl;
#pragma unroll 4
    for (int i = 0; i < 96; ++i) wdst[i * 64 + l] = wsrc[i * 64 + l];
  }

  // ---- XCD discovery (system scope, one-time; gates the fast path) ----
  bool fast;
  {
    unsigned int* gx = xcdbuf + grp * 16;
    unsigned int* gf = dflags + grp * 16;
    unsigned xcc;
    asm("s_getreg_b32 %0, hwreg(HW_REG_XCC_ID)" : "=s"(xcc));
    if (l == 0)
      __hip_atomic_store(gx + dt, xcc + 1u, __ATOMIC_RELAXED, __HIP_MEMORY_SCOPE_SYSTEM);
    asm volatile("s_waitcnt vmcnt(0)" ::: "memory");
    if (l == 0)
      __hip_atomic_store(gf + dt, 1u, __ATOMIC_RELAXED, __HIP_MEMORY_SCOPE_SYSTEM);
    unsigned f;
    do {
      f = __hip_atomic_load(gf + l15, __ATOMIC_RELAXED, __HIP_MEMORY_SCOPE_SYSTEM);
      if (__all((int)(f >= 1u))) break;
      __builtin_amdgcn_s_sleep(1);
    } while (true);
    asm volatile("" ::: "memory");
    unsigned x = __hip_atomic_load(gx + l15, __ATOMIC_RELAXED, __HIP_MEMORY_SCOPE_SYSTEM);
    unsigned x0 = __shfl(x, 0, 64);
    fast = (bool)__all((int)(x == x0));
  }
  __syncthreads();  // W staging complete

  // biases for this lane's two d-columns
  float br_[2], bz_[2], bn_[2];
#pragma unroll
  for (int n = 0; n < 2; ++n) {
    const int d = d0 + n * 16 + l15;
    br_[n] = bhh[d]; bz_[n] = bhh[512 + d]; bn_[n] = bhh[1024 + d];
  }

  // fp32 h carry
  float hp[2][4];
#pragma unroll
  for (int n = 0; n < 2; ++n)
#pragma unroll
    for (int r = 0; r < 4; ++r)
      hp[n][r] = h32_init ? h32_init[(size_t)(b0 + lh * 4 + r) * Dh + d0 + n * 16 + l15] : 0.f;

  // gi prefetch for step 0
  uint4 gpr[4];
#pragma unroll
  for (int r = 0; r < 4; ++r)
    gpr[r] = *(const uint4*)(gi + ((((size_t)0 * NB + b0 + lh * 4 + r) * 16 + dt) * 16 + l15) * 8);

  bool broken = false;  // watchdog: sticky, wave-uniform

  for (int s = 0; s < nsteps; ++s) {
    const unsigned short* rdbuf = (s == 0) ? rd0 : roll + (size_t)(s - 1) * NB * Dh;
    unsigned short* wrbuf = roll + (size_t)s * NB * Dh;

    // ---- wait for group's step-(s-1) outputs ----
    if (s > 0) {
      const unsigned int* fp = flags + (size_t)(s - 1) * 256 + grp * 16 + l15;
      if (fast) {
        if (!broken) {
          unsigned f;
          int tries = 0;
          while (true) {
            asm volatile("global_load_dword %0, %1, off sc0\n\ts_waitcnt vmcnt(0)"
                         : "=v"(f) : "v"(fp) : "memory");
            if (__all((int)(f != 0u))) break;
            if (++tries > (1 << 18)) { broken = true; break; }
            __builtin_amdgcn_s_sleep(2);
          }
        }
      } else {
        unsigned f;
        do {
          f = __hip_atomic_load(fp, __ATOMIC_RELAXED, __HIP_MEMORY_SCOPE_SYSTEM);
          if (__all((int)(f != 0u))) break;
          __builtin_amdgcn_s_sleep(1);
        } while (true);
        asm volatile("" ::: "memory");
      }
    }

    // ---- A-fragments (fresh addresses each step -> L1-cold plain loads) ----
    bf16x8 af[16];
    if (fast) {
      const bf16x8* ap = (const bf16x8*)(rdbuf + (size_t)(b0 + l15) * Dh + lh * 8);
#pragma unroll
      for (int kk = 0; kk < 16; ++kk) af[kk] = ap[kk * 4];
    } else {
      const u64t* ap = (const u64t*)(rdbuf + (size_t)(b0 + l15) * Dh + lh * 8);
#pragma unroll
      for (int kk = 0; kk < 16; ++kk) {
        union { u64t q[2]; bf16x8 v; } u;
        u.q[0] = __hip_atomic_load(ap + kk * 8, __ATOMIC_RELAXED, __HIP_MEMORY_SCOPE_SYSTEM);
        u.q[1] = __hip_atomic_load(ap + kk * 8 + 1, __ATOMIC_RELAXED, __HIP_MEMORY_SCOPE_SYSTEM);
        af[kk] = u.v;
      }
    }

    // ---- 96 MFMA from LDS-resident W ----
    f32x4 acc[6];
#pragma unroll
    for (int sl_ = 0; sl_ < 6; ++sl_) acc[sl_] = (f32x4)0.f;
#pragma unroll
    for (int sl_ = 0; sl_ < 6; ++sl_)
#pragma unroll
      for (int kk = 0; kk < 16; ++kk) {
        bf16x8 bv = *(const bf16x8*)&wl[((sl_ * 16 + kk) * 64 + l) * 8];
        acc[sl_] = __builtin_amdgcn_mfma_f32_16x16x32_bf16(af[kk], bv, acc[sl_], 0, 0, 0);
      }

    // ---- gates (lane-local) ----
#pragma unroll
    for (int n = 0; n < 2; ++n)
#pragma unroll
      for (int r = 0; r < 4; ++r) {
        const unsigned short* gp = (const unsigned short*)&gpr[r];
        const float gir = bf2f(gp[n * 3 + 0]);
        const float giz = bf2f(gp[n * 3 + 1]);
        const float gin = bf2f(gp[n * 3 + 2]);
        const float rr = 1.f / (1.f + __expf(-(gir + acc[n * 3 + 0][r] + br_[n])));
        const float zz = 1.f / (1.f + __expf(-(giz + acc[n * 3 + 1][r] + bz_[n])));
        const float x2 = gin + rr * (acc[n * 3 + 2][r] + bn_[n]);
        const float nn = 1.f - 2.f / (__expf(2.f * x2) + 1.f);  // tanh
        hp[n][r] = (1.f - zz) * nn + zz * hp[n][r];
      }

    // ---- publish bf16 h (packed u32 pairs) ----
#pragma unroll
    for (int n = 0; n < 2; ++n)
#pragma unroll
      for (int r = 0; r < 4; ++r) {
        const float po = __shfl_xor(hp[n][r], 1, 64);
        if ((l15 & 1) == 0) {
          const unsigned int pk = (unsigned)f2bf(hp[n][r]) | ((unsigned)f2bf(po) << 16);
          const int b = b0 + lh * 4 + r, d = d0 + n * 16 + l15;
          unsigned int* dst = (unsigned int*)(wrbuf + (size_t)b * Dh + d);
          if (fast) store_u32_sc0(dst, pk);  // sc0: dirty in shared XCD L2
          else __hip_atomic_store(dst, pk, __ATOMIC_RELAXED, __HIP_MEMORY_SCOPE_SYSTEM);
        }
      }

    if (s + 1 < nsteps) {
      asm volatile("s_waitcnt vmcnt(0)" ::: "memory");  // h stores acked (L2 fast path)
      if (l == 0) {
        unsigned int* fdst = flags + (size_t)s * 256 + grp * 16 + dt;
        if (fast) store_u32_sc0(fdst, 1u);
        else __hip_atomic_store(fdst, 1u, __ATOMIC_RELAXED, __HIP_MEMORY_SCOPE_SYSTEM);
      }
      // prefetch next step's gi under the upcoming poll
#pragma unroll
      for (int r = 0; r < 4; ++r)
        gpr[r] = *(const uint4*)(gi + ((((size_t)(s + 1) * NB + b0 + lh * 4 + r) * 16 + dt) * 16 + l15) * 8);
    }
  }

  if (h32_final) {
#pragma unroll
    for (int n = 0; n < 2; ++n)
#pragma unroll
      for (int r = 0; r < 4; ++r)
        h32_final[(size_t)(b0 + lh * 4 + r) * Dh + d0 + n * 16 + l15] = hp[n][r];
  }
}

// in-place log_softmax over last dim (512); one wave per row
__global__ __launch_bounds__(256) void logsoftmax512(float* __restrict__ x) {
  const int row = blockIdx.x * 4 + (threadIdx.x >> 6);
  const int lane = threadIdx.x & 63;
  float* p = x + (size_t)row * NV + lane * 8;
  float4 v0 = *(const float4*)p;
  float4 v1 = *(const float4*)(p + 4);
  float m = fmaxf(fmaxf(fmaxf(v0.x, v0.y), fmaxf(v0.z, v0.w)),
                  fmaxf(fmaxf(v1.x, v1.y), fmaxf(v1.z, v1.w)));
#pragma unroll
  for (int o = 1; o < 64; o <<= 1) m = fmaxf(m, __shfl_xor(m, o, 64));
  float s = expf(v0.x - m) + expf(v0.y - m) + expf(v0.z - m) + expf(v0.w - m) +
            expf(v1.x - m) + expf(v1.y - m) + expf(v1.z - m) + expf(v1.w - m);
#pragma unroll
  for (int o = 1; o < 64; o <<= 1) s += __shfl_xor(s, o, 64);
  const float ls = m + logf(s);
  v0.x -= ls; v0.y -= ls; v0.z -= ls; v0.w -= ls;
  v1.x -= ls; v1.y -= ls; v1.z -= ls; v1.w -= ls;
  *(float4*)p = v0;
  *(float4*)(p + 4) = v1;
}

extern "C" void kernel_launch(void* const* d_in, const int* in_sizes, int n_in,
                              void* d_out, int out_size, void* d_ws, size_t ws_size,
                              hipStream_t stream) {
  (void)in_sizes; (void)n_in; (void)out_size; (void)ws_size;
  const int* src = (const int*)d_in[0];
  const int* trg = (const int*)d_in[1];
  const float* enc_emb = (const float*)d_in[4];
  const float* enc_Wih = (const float*)d_in[5];
  const float* enc_Whh = (const float*)d_in[6];
  const float* enc_bih = (const float*)d_in[7];
  const float* enc_bhh = (const float*)d_in[8];
  const float* dec_emb = (const float*)d_in[9];
  const float* dec_Wih = (const float*)d_in[10];
  const float* dec_Whh = (const float*)d_in[11];
  const float* dec_bih = (const float*)d_in[12];
  const float* dec_bhh = (const float*)d_in[13];
  const float* out_W = (const float*)d_in[14];
  const float* out_b = (const float*)d_in[15];

  char* ws = (char*)d_ws;
  size_t off = 0;
  auto alloc = [&](size_t bytes) -> char* {
    char* p = ws + off;
    off += (bytes + 255) & ~(size_t)255;
    return p;
  };
  typedef unsigned short u16;
  u16* gi = (u16*)alloc((size_t)NB * SL * 16 * 16 * 8 * 2);  // 268 MB packed
  u16* hb_all = (u16*)alloc((size_t)TL * NB * Dh * 2);       // 67 MB rotation+archive
  float* h_enc = (float*)alloc((size_t)NB * Dh * 4);
  u16* hbZ = (u16*)alloc((size_t)NB * Dh * 2);               // zero h0
  u16* embB_e = (u16*)alloc((size_t)NV * Dh * 2);
  u16* embB_d = (u16*)alloc((size_t)NV * Dh * 2);            // relu pre-applied
  u16* WihB_e = (u16*)alloc((size_t)G3 * Dh * 2);
  u16* WhhB_e = (u16*)alloc((size_t)G3 * Dh * 2);
  u16* WihB_d = (u16*)alloc((size_t)G3 * Dh * 2);
  u16* WhhB_d = (u16*)alloc((size_t)G3 * Dh * 2);
  u16* outWB = (u16*)alloc((size_t)NV * Dh * 2);
  u16* Wpk_e = (u16*)alloc((size_t)16 * 6 * 16 * 64 * 8 * 2);  // 1.57 MB
  u16* Wpk_d = (u16*)alloc((size_t)16 * 6 * 16 * 64 * 8 * 2);
  unsigned int* flagsE = (unsigned int*)alloc((size_t)256 * 256 * 4);  // 256 KB
  unsigned int* flagsD = (unsigned int*)alloc((size_t)256 * 256 * 4);  // 256 KB
  unsigned int* xcdb = (unsigned int*)alloc(2 * 256 * 4);
  unsigned int* dflg = (unsigned int*)alloc(2 * 256 * 4);

  cvt_bf16<<<(NV * Dh / 4 + 255) / 256, 256, 0, stream>>>(enc_emb, embB_e, NV * Dh / 4, 0);
  cvt_bf16<<<(NV * Dh / 4 + 255) / 256, 256, 0, stream>>>(dec_emb, embB_d, NV * Dh / 4, 1);
  cvt_bf16<<<(G3 * Dh / 4 + 255) / 256, 256, 0, stream>>>(enc_Wih, WihB_e, G3 * Dh / 4, 0);
  cvt_bf16<<<(G3 * Dh / 4 + 255) / 256, 256, 0, stream>>>(enc_Whh, WhhB_e, G3 * Dh / 4, 0);
  cvt_bf16<<<(G3 * Dh / 4 + 255) / 256, 256, 0, stream>>>(dec_Wih, WihB_d, G3 * Dh / 4, 0);
  cvt_bf16<<<(G3 * Dh / 4 + 255) / 256, 256, 0, stream>>>(dec_Whh, WhhB_d, G3 * Dh / 4, 0);
  cvt_bf16<<<(NV * Dh / 4 + 255) / 256, 256, 0, stream>>>(out_W, outWB, NV * Dh / 4, 0);
  pack_whh<<<384, 256, 0, stream>>>(WhhB_e, Wpk_e);
  pack_whh<<<384, 256, 0, stream>>>(WhhB_d, Wpk_d);
  hipMemsetAsync(hbZ, 0, (size_t)NB * Dh * 2, stream);
  hipMemsetAsync(flagsE, 0, (size_t)256 * 256 * 4, stream);
  hipMemsetAsync(flagsD, 0, (size_t)256 * 256 * 4, stream);
  hipMemsetAsync(xcdb, 0, 2 * 256 * 4, stream);
  hipMemsetAsync(dflg, 0, 2 * 256 * 4, stream);

  // encoder gi (packed layout)
  dim3 ggi(G3 / 128, NB * SL / 128);
  gemm_bf16<0, 2><<<ggi, 256, 0, stream>>>(embB_e, src, WihB_e, enc_bih, gi, G3);

  // ---- encoder recurrence: rotation through hb_all; final h = hb_all[255] ----
  gru_persist5<<<dim3(256), 64, 0, stream>>>(Wpk_e, gi, enc_bhh, nullptr, h_enc,
                                             hbZ, hb_all, flagsE, xcdb, dflg, SL);

  // decoder gi (packed layout; stream-ordered after encoder reads done)
  gemm_bf16<0, 2><<<ggi, 256, 0, stream>>>(embB_d, trg, WihB_d, dec_bih, gi, G3);

  // ---- decoder recurrence: rd0 = encoder's final slot; in-place rotation ----
  gru_persist5<<<dim3(256), 64, 0, stream>>>(Wpk_d, gi, dec_bhh, h_enc, nullptr,
                                             hb_all + (size_t)(SL - 1) * NB * Dh,
                                             hb_all, flagsD, xcdb + 256, dflg + 256, TL);

  // logits = hb_all @ out_W^T + out_b -> d_out (fp32), then log_softmax
  dim3 glg(NV / 128, NB * TL / 128);
  gemm_bf16<1, 0><<<glg, 256, 0, stream>>>(hb_all, nullptr, outWB, out_b, d_out, NV);
  logsoftmax512<<<NB * TL / 4, 256, 0, stream>>>((float*)d_out);
}

// Round 11
// 4476.660 us; speedup vs baseline: 17.4735x; 17.4735x over previous
//
#include <hip/hip_runtime.h>
#include <cstdint>
#include <cstddef>

namespace {
constexpr int Dh = 512;   // hidden / emb dim
constexpr int G3 = 1536;  // 3*Dh
constexpr int NB = 256;   // batch
constexpr int SL = 256;   // src len
constexpr int TL = 256;   // trg len
constexpr int NV = 512;   // vocab
}

typedef __attribute__((ext_vector_type(8))) short bf16x8;
typedef __attribute__((ext_vector_type(4))) float f32x4;

__device__ __forceinline__ unsigned short f2bf(float f) {
  unsigned int u = __float_as_uint(f);
  u = (u + 0x7FFFu + ((u >> 16) & 1u)) >> 16;  // RNE (finite, small values)
  return (unsigned short)u;
}
__device__ __forceinline__ float bf2f(unsigned short s) {
  return __uint_as_float(((unsigned int)s) << 16);
}

// gi packed layout (consumer-native): [s][b][dt32(16)][l15(16)][8]
// slot n*3+g (n = d16-half within 32-d tile, g = gate), slots 6,7 padding.

// ---- fused fp32->bf16 conversion for emb_e, emb_d(relu), Wih_e, Wih_d ----
// float4-granular; segment bounds in float4 units.
__global__ __launch_bounds__(256) void cvt_all(
    const float* __restrict__ a0, const float* __restrict__ a1,
    const float* __restrict__ a2, const float* __restrict__ a3,
    unsigned short* __restrict__ o0, unsigned short* __restrict__ o1,
    unsigned short* __restrict__ o2, unsigned short* __restrict__ o3) {
  int i = blockIdx.x * 256 + threadIdx.x;  // 0..524287
  const float* src;
  unsigned short* dst;
  int base, rel = 0;
  if (i < 65536) { src = a0; dst = o0; base = 0; }
  else if (i < 131072) { src = a1; dst = o1; base = 65536; rel = 1; }
  else if (i < 327680) { src = a2; dst = o2; base = 131072; }
  else { src = a3; dst = o3; base = 327680; }
  int j = i - base;
  float4 v = ((const float4*)src)[j];
  if (rel) {
    v.x = fmaxf(v.x, 0.f); v.y = fmaxf(v.y, 0.f);
    v.z = fmaxf(v.z, 0.f); v.w = fmaxf(v.w, 0.f);
  }
  ushort4 o;
  o.x = f2bf(v.x); o.y = f2bf(v.y); o.z = f2bf(v.z); o.w = f2bf(v.w);
  ((ushort4*)dst)[j] = o;
}

// Pack Whh (fp32 [1536][512]) directly into bf16 lane-major fragment order:
// Wpk[dt(16)][slot(6)][kk(16)][lane(64)][8], slot = n*3+g. Both weights in one launch.
__global__ __launch_bounds__(256) void pack_whh_f32(
    const float* __restrict__ We, unsigned short* __restrict__ Pe,
    const float* __restrict__ Wd, unsigned short* __restrict__ Pd) {
  int idx = blockIdx.x * 256 + threadIdx.x;  // 0..196607
  if (idx >= 2 * 98304) return;
  const float* Wb = (idx < 98304) ? We : Wd;
  unsigned short* Wpk = (idx < 98304) ? Pe : Pd;
  if (idx >= 98304) idx -= 98304;
  const int dt = idx / 6144;
  const int rem = idx - dt * 6144;
  const int slot = rem >> 10;
  const int kk = (rem >> 6) & 15;
  const int l = rem & 63;
  const int n = slot / 3, g = slot - n * 3;
  const int row = g * 512 + dt * 32 + n * 16 + (l & 15);
  const int k = kk * 32 + (l >> 4) * 8;
  const float* s = Wb + (size_t)row * Dh + k;
  unsigned short o[8];
#pragma unroll
  for (int j = 0; j < 8; ++j) o[j] = f2bf(s[j]);
  *(uint4*)(Wpk + ((size_t)(idx < 0 ? 0 : 0) + (size_t)((dt * 6 + slot) * 16 + kk) * 64 + l) * 8) = *(uint4*)o;
}

// Pack out_W (fp32 [512][512]) into bf16 fragment order [nt(32)][kk(16)][lane(64)][8].
// Fragment (nt,kk,l): row = nt*16 + (l&15), k = kk*32 + (l>>4)*8.
__global__ __launch_bounds__(256) void pack_w16(const float* __restrict__ Wf,
                                                unsigned short* __restrict__ Wpk) {
  int idx = blockIdx.x * 256 + threadIdx.x;  // 0..32767
  if (idx >= 32 * 16 * 64) return;
  const int nt = idx >> 10;
  const int kk = (idx >> 6) & 15;
  const int l = idx & 63;
  const int row = nt * 16 + (l & 15);
  const int k = kk * 32 + (l >> 4) * 8;
  const float* s = Wf + (size_t)row * Dh + k;
  unsigned short o[8];
#pragma unroll
  for (int j = 0; j < 8; ++j) o[j] = f2bf(s[j]);
  *(uint4*)(Wpk + (size_t)idx * 8) = *(uint4*)o;
}

// gi GEMM: C[M,1536] = emb[idx] @ Wih^T + bih, bf16 out scattered to packed gi.
// MFMA 16x16x32, 128x128 tile, BK=64, 4 waves. (R2-proven structure.)
__global__ __launch_bounds__(256) void gemm_gi(
    const unsigned short* __restrict__ Abase, const int* __restrict__ idx,
    const unsigned short* __restrict__ W, const float* __restrict__ bias,
    unsigned short* __restrict__ Cout) {
  __shared__ unsigned short lds_a[8 * 128 * 8];  // 16 KB
  __shared__ unsigned short lds_b[8 * 128 * 8];  // 16 KB
  const int t = threadIdx.x;
  const int n0 = blockIdx.x * 128;
  const int m0 = blockIdx.y * 128;
  const int w = t >> 6, l = t & 63;
  const int mq = (w & 1) * 64, nq = (w >> 1) * 64;
  const int l15 = l & 15, lh = l >> 4;

  const int sm = t & 127;
  const int sk = (t >> 7) * 4;
  const unsigned short* arow = Abase + (size_t)idx[m0 + sm] * Dh;
  const unsigned short* brow = W + (size_t)(n0 + sm) * Dh;

  f32x4 acc[4][4];
#pragma unroll
  for (int i = 0; i < 4; ++i)
#pragma unroll
    for (int j = 0; j < 4; ++j) acc[i][j] = (f32x4)0.f;

  for (int k0 = 0; k0 < Dh; k0 += 64) {
    __syncthreads();
#pragma unroll
    for (int i = 0; i < 4; ++i) {
      int kc = sk + i;
      *(uint4*)&lds_a[(kc * 128 + sm) * 8] = *(const uint4*)(arow + k0 + kc * 8);
      *(uint4*)&lds_b[(kc * 128 + sm) * 8] = *(const uint4*)(brow + k0 + kc * 8);
    }
    __syncthreads();
#pragma unroll
    for (int q = 0; q < 2; ++q) {
      bf16x8 af[4], bfr[4];
#pragma unroll
      for (int i = 0; i < 4; ++i)
        af[i] = *(const bf16x8*)&lds_a[((q * 4 + lh) * 128 + mq + i * 16 + l15) * 8];
#pragma unroll
      for (int j = 0; j < 4; ++j)
        bfr[j] = *(const bf16x8*)&lds_b[((q * 4 + lh) * 128 + nq + j * 16 + l15) * 8];
#pragma unroll
      for (int i = 0; i < 4; ++i)
#pragma unroll
        for (int j = 0; j < 4; ++j)
          acc[i][j] = __builtin_amdgcn_mfma_f32_16x16x32_bf16(af[i], bfr[j], acc[i][j], 0, 0, 0);
    }
  }

#pragma unroll
  for (int j = 0; j < 4; ++j) {
    const int col = n0 + nq + j * 16 + l15;
    const float bv = bias[col];
#pragma unroll
    for (int i = 0; i < 4; ++i) {
#pragma unroll
      for (int r = 0; r < 4; ++r) {
        const int row = m0 + mq + i * 16 + lh * 4 + r;
        const float v = acc[i][j][r] + bv;
        const int b = row >> 8, s = row & 255;      // row = b*256 + s
        const int g = col >> 9, d = col & 511;
        const int dt = d >> 5, nn_ = (d >> 4) & 1, cl = d & 15;
        Cout[((((size_t)s * NB + b) * 16 + dt) * 16 + cl) * 8 + nn_ * 3 + g] = f2bf(v);
      }
    }
  }
}

// ---- shared per-wave GRU tile body (16 batches x 32 d x 3 gates, K=512) ----
// W from packed lane-major layout (coalesced 1KB loads, L2-resident slice).
__device__ __forceinline__ void gru_tile_body(
    const unsigned short* __restrict__ Wpk,  // [16][6][16][64][8]
    const unsigned short* __restrict__ gi,   // packed (incl. bih)
    const float* __restrict__ bhh,
    const float* __restrict__ h32_in, float* __restrict__ h32_out,
    const unsigned short* __restrict__ hb_in, unsigned short* __restrict__ hb_out,
    int s, int wt, int l) {
  const int b0 = (wt >> 4) * 16;
  const int dt = wt & 15, d0 = dt * 32;
  const int l15 = l & 15, lh = l >> 4;

  // A-fragments: h rows b0+l15, k = kk*32 + lh*8
  bf16x8 af[16];
#pragma unroll
  for (int kk = 0; kk < 16; ++kk)
    af[kk] = *(const bf16x8*)(hb_in + (size_t)(b0 + l15) * Dh + kk * 32 + lh * 8);

  // gi packed loads: one uint4 per r
  uint4 gpr[4];
#pragma unroll
  for (int r = 0; r < 4; ++r)
    gpr[r] = *(const uint4*)(gi + ((((size_t)s * NB + b0 + lh * 4 + r) * 16 + dt) * 16 + l15) * 8);

  // fp32 h carry
  float hp[2][4];
#pragma unroll
  for (int n = 0; n < 2; ++n)
#pragma unroll
    for (int r = 0; r < 4; ++r)
      hp[n][r] = h32_in[(size_t)(b0 + lh * 4 + r) * Dh + d0 + n * 16 + l15];

  f32x4 acc[2][3];
#pragma unroll
  for (int n = 0; n < 2; ++n)
#pragma unroll
    for (int g = 0; g < 3; ++g) acc[n][g] = (f32x4)0.f;

  const unsigned short* wb = Wpk + ((size_t)dt * 6144 + l) * 8;  // + (slot*16+kk)*64*8
#pragma unroll
  for (int n = 0; n < 2; ++n)
#pragma unroll
    for (int g = 0; g < 3; ++g) {
      const int slot = n * 3 + g;
      bf16x8 bv[16];
#pragma unroll
      for (int kk = 0; kk < 16; ++kk)
        bv[kk] = *(const bf16x8*)(wb + (size_t)(slot * 16 + kk) * 64 * 8);
#pragma unroll
      for (int kk = 0; kk < 16; ++kk)
        acc[n][g] = __builtin_amdgcn_mfma_f32_16x16x32_bf16(af[kk], bv[kk], acc[n][g], 0, 0, 0);
    }

  // gates: lane-local. D row (batch) = lh*4+r, col = l15.
#pragma unroll
  for (int n = 0; n < 2; ++n) {
    const int d = d0 + n * 16 + l15;
    const float br = bhh[d], bz = bhh[512 + d], bn = bhh[1024 + d];
#pragma unroll
    for (int r = 0; r < 4; ++r) {
      const unsigned short* gp = (const unsigned short*)&gpr[r];
      const float gir = bf2f(gp[n * 3 + 0]);
      const float giz = bf2f(gp[n * 3 + 1]);
      const float gin = bf2f(gp[n * 3 + 2]);
      const float rr = 1.f / (1.f + __expf(-(gir + acc[n][0][r] + br)));
      const float zz = 1.f / (1.f + __expf(-(giz + acc[n][1][r] + bz)));
      const float x2 = gin + rr * (acc[n][2][r] + bn);
      const float nn = 1.f - 2.f / (__expf(2.f * x2) + 1.f);  // tanh
      const float o = (1.f - zz) * nn + zz * hp[n][r];
      const int b = b0 + lh * 4 + r;
      h32_out[(size_t)b * Dh + d] = o;
      hb_out[(size_t)b * Dh + d] = f2bf(o);
    }
  }
}

// ---- A/B arm 1: 256 WGs x 64 thr (1 wave/WG) — R6-proven ----
__global__ __launch_bounds__(64, 1) void gru_step3(
    const unsigned short* __restrict__ Wpk, const unsigned short* __restrict__ gi,
    const float* __restrict__ bhh,
    const float* __restrict__ h32_in, float* __restrict__ h32_out,
    const unsigned short* __restrict__ hb_in, unsigned short* __restrict__ hb_out,
    int s) {
  gru_tile_body(Wpk, gi, bhh, h32_in, h32_out, hb_in, hb_out, s,
                blockIdx.x, threadIdx.x & 63);
}

// ---- A/B arm 2: 64 WGs x 256 thr (4 independent wave-tiles/WG) ----
__global__ __launch_bounds__(256, 1) void gru_step4w(
    const unsigned short* __restrict__ Wpk, const unsigned short* __restrict__ gi,
    const float* __restrict__ bhh,
    const float* __restrict__ h32_in, float* __restrict__ h32_out,
    const unsigned short* __restrict__ hb_in, unsigned short* __restrict__ hb_out,
    int s) {
  gru_tile_body(Wpk, gi, bhh, h32_in, h32_out, hb_in, hb_out, s,
                blockIdx.x * 4 + (threadIdx.x >> 6), threadIdx.x & 63);
}

// ---- fused logits + log_softmax: one WG = 32 out-rows x full 512 vocab ----
// out[b*256+t][v] = log_softmax(hb_all[t][b] @ outW^T + out_b).
__global__ __launch_bounds__(256, 1) void logits_ls(
    const unsigned short* __restrict__ hb_all,  // [t][b][512] bf16
    const unsigned short* __restrict__ Wpk,     // [32][16][64][8] packed out_W
    const float* __restrict__ out_b,
    float* __restrict__ out) {                  // [65536][512] fp32
  __shared__ unsigned short Alds[64 * 32 * 8];  // [kc][row][8] = 32 KB
  __shared__ float redm[4][32];
  __shared__ float reds[4][32];
  const int m0 = blockIdx.x * 32;
  const int t = threadIdx.x;
  const int w = t >> 6, l = t & 63;
  const int l15 = l & 15, lh = l >> 4;

  // stage A (32 rows x 512 k): 2048 16B chunks, coalesced per row
#pragma unroll
  for (int i = 0; i < 8; ++i) {
    int id = i * 256 + t;
    int row = id >> 6, kc = id & 63;
    int orow = m0 + row;
    int arow = (orow & 255) * NB + (orow >> 8);  // out-row (b,t) -> hb_all[t][b]
    *(uint4*)&Alds[(kc * 32 + row) * 8] = *(const uint4*)(hb_all + (size_t)arow * Dh + kc * 8);
  }
  __syncthreads();

  // A-frags for both 16-row tiles
  bf16x8 af[2][16];
#pragma unroll
  for (int mi = 0; mi < 2; ++mi)
#pragma unroll
    for (int kk = 0; kk < 16; ++kk)
      af[mi][kk] = *(const bf16x8*)&Alds[((kk * 4 + lh) * 32 + mi * 16 + l15) * 8];

  f32x4 acc[2][8];
#pragma unroll
  for (int mi = 0; mi < 2; ++mi)
#pragma unroll
    for (int j = 0; j < 8; ++j) acc[mi][j] = (f32x4)0.f;

#pragma unroll
  for (int j = 0; j < 8; ++j) {
    const int nt = w * 8 + j;
    const unsigned short* bp = Wpk + ((size_t)(nt * 16) * 64 + l) * 8;
    bf16x8 bv[16];
#pragma unroll
    for (int kk = 0; kk < 16; ++kk) bv[kk] = *(const bf16x8*)(bp + (size_t)kk * 64 * 8);
#pragma unroll
    for (int kk = 0; kk < 16; ++kk) {
      acc[0][j] = __builtin_amdgcn_mfma_f32_16x16x32_bf16(af[0][kk], bv[kk], acc[0][j], 0, 0, 0);
      acc[1][j] = __builtin_amdgcn_mfma_f32_16x16x32_bf16(af[1][kk], bv[kk], acc[1][j], 0, 0, 0);
    }
  }

  // bias add (col = (w*8+j)*16 + l15)
#pragma unroll
  for (int j = 0; j < 8; ++j) {
    const float bc = out_b[(w * 8 + j) * 16 + l15];
#pragma unroll
    for (int mi = 0; mi < 2; ++mi)
#pragma unroll
      for (int r = 0; r < 4; ++r) acc[mi][j][r] += bc;
  }

  // row-wise max: lane covers rows (mi*16 + lh*4 + r), cols {(w*8+j)*16+l15}
  float gmax[2][4];
#pragma unroll
  for (int mi = 0; mi < 2; ++mi)
#pragma unroll
    for (int r = 0; r < 4; ++r) {
      float m = acc[mi][0][r];
#pragma unroll
      for (int j = 1; j < 8; ++j) m = fmaxf(m, acc[mi][j][r]);
#pragma unroll
      for (int off = 1; off < 16; off <<= 1) m = fmaxf(m, __shfl_xor(m, off, 16));
      if (l15 == 0) redm[w][mi * 16 + lh * 4 + r] = m;
      gmax[mi][r] = m;  // wave-local for now
    }
  __syncthreads();
#pragma unroll
  for (int mi = 0; mi < 2; ++mi)
#pragma unroll
    for (int r = 0; r < 4; ++r) {
      const int row = mi * 16 + lh * 4 + r;
      gmax[mi][r] = fmaxf(fmaxf(redm[0][row], redm[1][row]),
                          fmaxf(redm[2][row], redm[3][row]));
    }

  // row-wise sum of exp
  float ls[2][4];
#pragma unroll
  for (int mi = 0; mi < 2; ++mi)
#pragma unroll
    for (int r = 0; r < 4; ++r) {
      float sv = 0.f;
#pragma unroll
      for (int j = 0; j < 8; ++j) sv += expf(acc[mi][j][r] - gmax[mi][r]);
#pragma unroll
      for (int off = 1; off < 16; off <<= 1) sv += __shfl_xor(sv, off, 16);
      if (l15 == 0) reds[w][mi * 16 + lh * 4 + r] = sv;
    }
  __syncthreads();
#pragma unroll
  for (int mi = 0; mi < 2; ++mi)
#pragma unroll
    for (int r = 0; r < 4; ++r) {
      const int row = mi * 16 + lh * 4 + r;
      const float tot = reds[0][row] + reds[1][row] + reds[2][row] + reds[3][row];
      ls[mi][r] = gmax[mi][r] + logf(tot);
    }

  // write log-softmaxed values
#pragma unroll
  for (int mi = 0; mi < 2; ++mi)
#pragma unroll
    for (int j = 0; j < 8; ++j) {
      const int col = (w * 8 + j) * 16 + l15;
#pragma unroll
      for (int r = 0; r < 4; ++r) {
        const size_t row = (size_t)m0 + mi * 16 + lh * 4 + r;
        out[row * NV + col] = acc[mi][j][r] - ls[mi][r];
      }
    }
}

extern "C" void kernel_launch(void* const* d_in, const int* in_sizes, int n_in,
                              void* d_out, int out_size, void* d_ws, size_t ws_size,
                              hipStream_t stream) {
  (void)in_sizes; (void)n_in; (void)out_size; (void)ws_size;
  const int* src = (const int*)d_in[0];
  const int* trg = (const int*)d_in[1];
  const float* enc_emb = (const float*)d_in[4];
  const float* enc_Wih = (const float*)d_in[5];
  const float* enc_Whh = (const float*)d_in[6];
  const float* enc_bih = (const float*)d_in[7];
  const float* enc_bhh = (const float*)d_in[8];
  const float* dec_emb = (const float*)d_in[9];
  const float* dec_Wih = (const float*)d_in[10];
  const float* dec_Whh = (const float*)d_in[11];
  const float* dec_bih = (const float*)d_in[12];
  const float* dec_bhh = (const float*)d_in[13];
  const float* out_W = (const float*)d_in[14];
  const float* out_b = (const float*)d_in[15];

  char* ws = (char*)d_ws;
  size_t off = 0;
  auto alloc = [&](size_t bytes) -> char* {
    char* p = ws + off;
    off += (bytes + 255) & ~(size_t)255;
    return p;
  };
  typedef unsigned short u16;
  u16* gi = (u16*)alloc((size_t)NB * SL * 16 * 16 * 8 * 2);  // 268 MB packed
  u16* hb_all = (u16*)alloc((size_t)TL * NB * Dh * 2);       // 67 MB
  float* h32a = (float*)alloc((size_t)NB * Dh * 4);
  float* h32b = (float*)alloc((size_t)NB * Dh * 4);
  u16* hb0 = (u16*)alloc((size_t)NB * Dh * 2);
  u16* hb1 = (u16*)alloc((size_t)NB * Dh * 2);
  u16* embB_e = (u16*)alloc((size_t)NV * Dh * 2);
  u16* embB_d = (u16*)alloc((size_t)NV * Dh * 2);            // relu pre-applied
  u16* WihB_e = (u16*)alloc((size_t)G3 * Dh * 2);
  u16* WihB_d = (u16*)alloc((size_t)G3 * Dh * 2);
  u16* Wpk_e = (u16*)alloc((size_t)16 * 6 * 16 * 64 * 8 * 2);  // 1.57 MB
  u16* Wpk_d = (u16*)alloc((size_t)16 * 6 * 16 * 64 * 8 * 2);
  u16* outWpk = (u16*)alloc((size_t)32 * 16 * 64 * 8 * 2);     // 512 KB

  // ---- prologue: 3 kernels + 2 memsets ----
  cvt_all<<<2048, 256, 0, stream>>>(enc_emb, dec_emb, enc_Wih, dec_Wih,
                                    embB_e, embB_d, WihB_e, WihB_d);
  pack_whh_f32<<<768, 256, 0, stream>>>(enc_Whh, Wpk_e, dec_Whh, Wpk_d);
  pack_w16<<<128, 256, 0, stream>>>(out_W, outWpk);
  hipMemsetAsync(h32a, 0, (size_t)NB * Dh * 4, stream);  // fp32 h0 = 0
  hipMemsetAsync(hb0, 0, (size_t)NB * Dh * 2, stream);   // bf16 h0 = 0

  // ---- encoder gi (packed layout) ----
  dim3 ggi(G3 / 128, NB * SL / 128);
  gemm_gi<<<ggi, 256, 0, stream>>>(embB_e, src, WihB_e, enc_bih, gi);

  // ---- encoder recurrence: A/B arm = 64 WGs x 256 thr ----
  for (int s = 0; s < SL; ++s) {
    const float* i32 = (s & 1) ? h32b : h32a;
    float* o32 = (s & 1) ? h32a : h32b;
    const u16* ib = (s & 1) ? hb1 : hb0;
    u16* ob = (s & 1) ? hb0 : hb1;
    gru_step4w<<<dim3(64), 256, 0, stream>>>(Wpk_e, gi, enc_bhh, i32, o32, ib, ob, s);
  }
  // SL=256 even -> final encoder state in h32a / hb0

  // ---- decoder gi (packed; overwrites gi after encoder reads done) ----
  gemm_gi<<<ggi, 256, 0, stream>>>(embB_d, trg, WihB_d, dec_bih, gi);

  // ---- decoder recurrence: R6-proven 256 WGs x 64 thr; h archived to hb_all ----
  for (int s = 0; s < TL; ++s) {
    const float* i32 = (s & 1) ? h32b : h32a;
    float* o32 = (s & 1) ? h32a : h32b;
    const u16* ib = (s == 0) ? hb0 : (hb_all + (size_t)(s - 1) * NB * Dh);
    u16* ob = hb_all + (size_t)s * NB * Dh;
    gru_step3<<<dim3(256), 64, 0, stream>>>(Wpk_d, gi, dec_bhh, i32, o32, ib, ob, s);
  }

  // ---- fused logits + log_softmax -> d_out ----
  logits_ls<<<dim3(NB * TL / 32), 256, 0, stream>>>(hb_all, outWpk, out_b, (float*)d_out);
}